// Round 1
// baseline (144.381 us; speedup 1.0000x reference)
//
#include <hip/hip_runtime.h>
#include <hip/hip_bf16.h>
#include <stdint.h>

// Problem constants: B=8, S=2048, D=1024, E=8, CAP=512, TOK = 16384.
// Outputs (concatenated f32): hidden[16384*1024], logits[16384*8], expert_index[16384]

typedef __attribute__((ext_vector_type(8))) short short8;   // 8 x bf16 (4 VGPRs)
typedef __attribute__((ext_vector_type(4))) float f32x4;

#define AS1 __attribute__((address_space(1)))
#define AS3 __attribute__((address_space(3)))

static __device__ __forceinline__ uint32_t f2bf(float f) {
  __hip_bfloat16 h = __float2bfloat16(f);
  return (uint32_t)*reinterpret_cast<unsigned short*>(&h);
}

// ---------------- Kernel 1: router (logits f32, softmax top-1) + x -> bf16 ----
__global__ __launch_bounds__(256) void k_router(
    const float* __restrict__ x, const float* __restrict__ gw,
    __hip_bfloat16* __restrict__ xb, float* __restrict__ logits,
    float* __restrict__ tprob, int* __restrict__ texp) {
  __shared__ __align__(16) float gs[8 * 1024];  // gate weights [e][d]
  const int tid = threadIdx.x;
  {
    const float4* g4 = reinterpret_cast<const float4*>(gw);
    float4* s4 = reinterpret_cast<float4*>(gs);
#pragma unroll
    for (int i = 0; i < 8; ++i) s4[tid + 256 * i] = g4[tid + 256 * i];
  }
  __syncthreads();
  const int wave = tid >> 6, lane = tid & 63;
  const int t = blockIdx.x * 4 + wave;  // one wave per token, 4096 blocks
  const float2* x2 = reinterpret_cast<const float2*>(x + (size_t)t * 1024);
  uint32_t* xbu = reinterpret_cast<uint32_t*>(xb + (size_t)t * 1024);
  const float2* g2 = reinterpret_cast<const float2*>(gs);
  float acc[8];
#pragma unroll
  for (int e = 0; e < 8; ++e) acc[e] = 0.f;
#pragma unroll
  for (int kk = 0; kk < 8; ++kk) {
    int p = lane + 64 * kk;  // float2-pair index, lane-stride-1 (conflict-free LDS)
    float2 xv = x2[p];
    xbu[p] = f2bf(xv.x) | (f2bf(xv.y) << 16);
#pragma unroll
    for (int e = 0; e < 8; ++e) {
      float2 g = g2[e * 512 + p];
      acc[e] = fmaf(xv.x, g.x, acc[e]);
      acc[e] = fmaf(xv.y, g.y, acc[e]);
    }
  }
#pragma unroll
  for (int d = 1; d < 64; d <<= 1) {
#pragma unroll
    for (int e = 0; e < 8; ++e) acc[e] += __shfl_xor(acc[e], d, 64);
  }
  if (lane == 0) {
    float m = acc[0];
    int idx = 0;
#pragma unroll
    for (int e = 1; e < 8; ++e)
      if (acc[e] > m) { m = acc[e]; idx = e; }  // strict '>' == argmax-first tiebreak
    float s = 0.f;
#pragma unroll
    for (int e = 0; e < 8; ++e) s += expf(acc[e] - m);
    tprob[t] = 1.0f / s;   // softmax prob of the max logit
    texp[t] = idx;
#pragma unroll
    for (int e = 0; e < 8; ++e) logits[(size_t)t * 8 + e] = acc[e];
  }
}

// ---------------- Kernel 2: expert_w [e][k][n] f32 -> Wt [e][n][k] bf16 -------
__global__ __launch_bounds__(256) void k_wconv(const float* __restrict__ w,
                                               __hip_bfloat16* __restrict__ wt) {
  // grid = 8 * 32 * 32 tiles of 32x32
  const int bx = blockIdx.x;
  const int e = bx >> 10;
  const int rem = bx & 1023;
  const int k0 = (rem >> 5) << 5;
  const int n0 = (rem & 31) << 5;
  __shared__ float tile[32][33];  // +1 pad: no bank conflicts on transpose
  const int tid = threadIdx.x;
  const int c = tid & 31, r0 = tid >> 5;
  const float* ws = w + (size_t)e * 1024 * 1024;
#pragma unroll
  for (int i = 0; i < 4; ++i) {
    int r = r0 + 8 * i;
    tile[r][c] = ws[(size_t)(k0 + r) * 1024 + n0 + c];
  }
  __syncthreads();
  __hip_bfloat16* wd = wt + (size_t)e * 1024 * 1024;
#pragma unroll
  for (int i = 0; i < 4; ++i) {
    int r = r0 + 8 * i;  // n within tile
    wd[(size_t)(n0 + r) * 1024 + k0 + c] = __float2bfloat16(tile[c][r]);
  }
}

// ---------------- Kernel 3: per-batch capacity scan (cumsum of onehot) --------
__global__ __launch_bounds__(256) void k_scan(
    const int* __restrict__ texp, int* __restrict__ slots, int* __restrict__ neb,
    int* __restrict__ keep, float* __restrict__ idx_out) {
  const int b = blockIdx.x;  // grid = 8
  const int tid = threadIdx.x;
  __shared__ int te_s[2048];
#pragma unroll
  for (int i = 0; i < 8; ++i) te_s[tid + 256 * i] = texp[b * 2048 + tid + 256 * i];
  __syncthreads();

  int myte[8], cnt[8];
#pragma unroll
  for (int e = 0; e < 8; ++e) cnt[e] = 0;
#pragma unroll
  for (int j = 0; j < 8; ++j) {  // thread owns 8 consecutive tokens
    int v = te_s[tid * 8 + j];
    myte[j] = v;
#pragma unroll
    for (int e = 0; e < 8; ++e) cnt[e] += (v == e);
  }
  // pack 8 counters into 4 u32 (16-bit fields; totals <= 2048 < 65536)
  unsigned u0 = (unsigned)cnt[0] | ((unsigned)cnt[1] << 16);
  unsigned u1 = (unsigned)cnt[2] | ((unsigned)cnt[3] << 16);
  unsigned u2 = (unsigned)cnt[4] | ((unsigned)cnt[5] << 16);
  unsigned u3 = (unsigned)cnt[6] | ((unsigned)cnt[7] << 16);
  const int lane = tid & 63, wave = tid >> 6;
#pragma unroll
  for (int d = 1; d < 64; d <<= 1) {  // inclusive scan within wave
    unsigned v0 = __shfl_up(u0, d, 64);
    unsigned v1 = __shfl_up(u1, d, 64);
    unsigned v2 = __shfl_up(u2, d, 64);
    unsigned v3 = __shfl_up(u3, d, 64);
    if (lane >= d) { u0 += v0; u1 += v1; u2 += v2; u3 += v3; }
  }
  __shared__ unsigned wtot[4][4];
  if (lane == 63) { wtot[wave][0] = u0; wtot[wave][1] = u1; wtot[wave][2] = u2; wtot[wave][3] = u3; }
  __syncthreads();
  unsigned a0 = 0, a1 = 0, a2 = 0, a3 = 0, s0 = 0, s1 = 0, s2 = 0, s3 = 0;
#pragma unroll
  for (int w = 0; w < 4; ++w) {
    unsigned q0 = wtot[w][0], q1 = wtot[w][1], q2 = wtot[w][2], q3 = wtot[w][3];
    if (w < wave) { a0 += q0; a1 += q1; a2 += q2; a3 += q3; }
    s0 += q0; s1 += q1; s2 += q2; s3 += q3;
  }
  u0 += a0; u1 += a1; u2 += a2; u3 += a3;  // inclusive over whole block
  int base[8];
  base[0] = (int)(u0 & 0xFFFF) - cnt[0]; base[1] = (int)(u0 >> 16) - cnt[1];
  base[2] = (int)(u1 & 0xFFFF) - cnt[2]; base[3] = (int)(u1 >> 16) - cnt[3];
  base[4] = (int)(u2 & 0xFFFF) - cnt[4]; base[5] = (int)(u2 >> 16) - cnt[5];
  base[6] = (int)(u3 & 0xFFFF) - cnt[6]; base[7] = (int)(u3 >> 16) - cnt[7];
  if (tid == 0) {
    int tt[8] = {(int)(s0 & 0xFFFF), (int)(s0 >> 16), (int)(s1 & 0xFFFF), (int)(s1 >> 16),
                 (int)(s2 & 0xFFFF), (int)(s2 >> 16), (int)(s3 & 0xFFFF), (int)(s3 >> 16)};
#pragma unroll
    for (int e = 0; e < 8; ++e) neb[e * 8 + b] = tt[e] < 512 ? tt[e] : 512;
  }
#pragma unroll
  for (int j = 0; j < 8; ++j) {
    int v = myte[j];
    int rank = 0;
#pragma unroll
    for (int e = 0; e < 8; ++e)
      if (v == e) { base[e] += 1; rank = base[e]; }  // 1-based inclusive rank
    int tok = b * 2048 + tid * 8 + j;
    int kp = rank <= 512;
    keep[tok] = kp;
    idx_out[tok] = kp ? (float)v : 0.0f;  // argmax(all-zero mask)=0 for dropped
    if (kp) slots[v * 4096 + b * 512 + rank - 1] = tok;  // deterministic, no atomics
  }
}

// ---------------- Kernel 4: gathered expert GEMM (bf16 MFMA, 128x128xBK32) ----
__global__ __launch_bounds__(256) void k_gemm(
    const __hip_bfloat16* __restrict__ xb, const __hip_bfloat16* __restrict__ wt,
    const int* __restrict__ slots, const int* __restrict__ neb,
    const float* __restrict__ tprob, float* __restrict__ out) {
  // grid 2048 = e(8) x b(8) x rowtile(4) x coltile(8)
  const int bx = blockIdx.x;
  const int e = bx >> 8;
  const int rem = bx & 255;
  const int bb = rem >> 5;
  const int rt = (rem >> 3) & 3;
  const int ct = rem & 7;
  int nvalid = neb[e * 8 + bb] - rt * 128;
  if (nvalid <= 0) return;
  if (nvalid > 128) nvalid = 128;

  __shared__ __align__(16) __hip_bfloat16 As[128 * 32];  // [row][k]
  __shared__ __align__(16) __hip_bfloat16 Bs[128 * 32];  // [n][k] (Wt layout)
  __shared__ int rid_s[128];
  __shared__ float tp_s[128];

  const int tid = threadIdx.x;
  const int* seg = slots + e * 4096 + bb * 512 + rt * 128;
  if (tid < 128) {
    int rid = seg[(tid < nvalid) ? tid : 0];  // dummy rows -> row 0 (store-masked)
    rid_s[tid] = rid;
    tp_s[tid] = tprob[rid];
  }
  __syncthreads();

  const int wave = tid >> 6, lane = tid & 63;
  const int wm = wave >> 1, wn = wave & 1;  // 2x2 wave grid, 64x64 per wave

  // staging: 512 chunks of 16B per 8KB tile; chunk cid -> lds elem cid*8,
  // row = cid>>2, kchunk = cid&3. Wave-uniform LDS base + lane*16 (HW rule).
  const int cid0 = wave * 64 + lane;
  const int cid1 = 256 + cid0;
  const int ar0 = cid0 >> 2, ac0 = cid0 & 3;
  const int ar1 = cid1 >> 2, ac1 = cid1 & 3;

  const __hip_bfloat16* wte = wt + (size_t)e * 1024 * 1024;
  const __hip_bfloat16* pa0 = xb + (size_t)rid_s[ar0] * 1024 + ac0 * 8;
  const __hip_bfloat16* pa1 = xb + (size_t)rid_s[ar1] * 1024 + ac1 * 8;
  const __hip_bfloat16* pb0 = wte + (size_t)(ct * 128 + ar0) * 1024 + ac0 * 8;
  const __hip_bfloat16* pb1 = wte + (size_t)(ct * 128 + ar1) * 1024 + ac1 * 8;

  __hip_bfloat16* lA0 = As + wave * 512;
  __hip_bfloat16* lA1 = As + 2048 + wave * 512;
  __hip_bfloat16* lB0 = Bs + wave * 512;
  __hip_bfloat16* lB1 = Bs + 2048 + wave * 512;

  f32x4 acc[4][4];
#pragma unroll
  for (int i = 0; i < 4; ++i)
#pragma unroll
    for (int j = 0; j < 4; ++j) acc[i][j] = 0.f;

  const int frow = lane & 15;
  const int fk = (lane >> 4) * 8;

  for (int kt = 0; kt < 1024; kt += 32) {
    __syncthreads();
    __builtin_amdgcn_global_load_lds((const AS1 uint32_t*)(pa0 + kt), (AS3 uint32_t*)lA0, 16, 0, 0);
    __builtin_amdgcn_global_load_lds((const AS1 uint32_t*)(pa1 + kt), (AS3 uint32_t*)lA1, 16, 0, 0);
    __builtin_amdgcn_global_load_lds((const AS1 uint32_t*)(pb0 + kt), (AS3 uint32_t*)lB0, 16, 0, 0);
    __builtin_amdgcn_global_load_lds((const AS1 uint32_t*)(pb1 + kt), (AS3 uint32_t*)lB1, 16, 0, 0);
    __syncthreads();

    short8 a[4], b[4];
#pragma unroll
    for (int mi = 0; mi < 4; ++mi)
      a[mi] = *reinterpret_cast<const short8*>(&As[(wm * 64 + mi * 16 + frow) * 32 + fk]);
#pragma unroll
    for (int ni = 0; ni < 4; ++ni)
      b[ni] = *reinterpret_cast<const short8*>(&Bs[(wn * 64 + ni * 16 + frow) * 32 + fk]);
#pragma unroll
    for (int mi = 0; mi < 4; ++mi)
#pragma unroll
      for (int ni = 0; ni < 4; ++ni)
        acc[mi][ni] = __builtin_amdgcn_mfma_f32_16x16x32_bf16(a[mi], b[ni], acc[mi][ni], 0, 0, 0);
  }

  // C/D layout: col = lane&15, row = (lane>>4)*4 + j   [m89-verified]
  const int colb = ct * 128 + wn * 64 + (lane & 15);
  const int rowb = wm * 64 + (lane >> 4) * 4;
#pragma unroll
  for (int mi = 0; mi < 4; ++mi) {
#pragma unroll
    for (int j = 0; j < 4; ++j) {
      int r = rowb + mi * 16 + j;
      if (r < nvalid) {
        size_t ro = (size_t)rid_s[r] * 1024;
        float sc = tp_s[r];
#pragma unroll
        for (int ni = 0; ni < 4; ++ni)
          out[ro + colb + ni * 16] = sc * acc[mi][ni][j];
      }
    }
  }
}

// ---------------- Kernel 5: identity pass-through for dropped tokens ----------
__global__ __launch_bounds__(256) void k_identity(
    const float* __restrict__ x, const float* __restrict__ tprob,
    const int* __restrict__ keep, float* __restrict__ out) {
  const int t0 = blockIdx.x * 8;  // grid = 2048
  const int tid = threadIdx.x;
#pragma unroll
  for (int j = 0; j < 8; ++j) {
    int t = t0 + j;
    if (!keep[t]) {
      float s = tprob[t];
      const float4* xi = reinterpret_cast<const float4*>(x + (size_t)t * 1024);
      float4* o = reinterpret_cast<float4*>(out + (size_t)t * 1024);
      float4 v = xi[tid];
      o[tid] = make_float4(s * v.x, s * v.y, s * v.z, s * v.w);
    }
  }
}

extern "C" void kernel_launch(void* const* d_in, const int* in_sizes, int n_in,
                              void* d_out, int out_size, void* d_ws, size_t ws_size,
                              hipStream_t stream) {
  const float* x = (const float*)d_in[0];    // [8,2048,1024]
  const float* gw = (const float*)d_in[1];   // [8,1024]
  const float* w = (const float*)d_in[2];    // [8,1024,1024]
  float* out = (float*)d_out;
  float* logits = out + (size_t)16384 * 1024;
  float* idx_out = logits + (size_t)16384 * 8;

  // workspace layout (~48.3 MB total)
  char* ws = (char*)d_ws;
  __hip_bfloat16* xb = (__hip_bfloat16*)(ws);              // 33554432 B
  __hip_bfloat16* wt = (__hip_bfloat16*)(ws + 33554432);   // 16777216 B
  float* tprob = (float*)(ws + 50331648);                  // 65536 B
  int* texp   = (int*)(ws + 50397184);                     // 65536 B
  int* keep   = (int*)(ws + 50462720);                     // 65536 B
  int* slots  = (int*)(ws + 50528256);                     // 131072 B
  int* neb    = (int*)(ws + 50659328);                     // 256 B

  hipLaunchKernelGGL(k_router,   dim3(4096), dim3(256), 0, stream, x, gw, xb, logits, tprob, texp);
  hipLaunchKernelGGL(k_wconv,    dim3(8192), dim3(256), 0, stream, w, wt);
  hipLaunchKernelGGL(k_scan,     dim3(8),    dim3(256), 0, stream, texp, slots, neb, keep, idx_out);
  hipLaunchKernelGGL(k_gemm,     dim3(2048), dim3(256), 0, stream, xb, wt, slots, neb, tprob, out);
  hipLaunchKernelGGL(k_identity, dim3(2048), dim3(256), 0, stream, x, tprob, keep, out);
}

// Round 2
// 113.421 us; speedup vs baseline: 1.2730x; 1.2730x over previous
//
#include <hip/hip_runtime.h>
#include <hip/hip_bf16.h>
#include <stdint.h>

// Problem: B=8, S=2048, D=1024, E=8, CAP=512, TOK=16384.
// Outputs (concat f32): hidden[16384*1024], logits[16384*8], expert_index[16384]

typedef __attribute__((ext_vector_type(8))) short short8;   // 8 x bf16 (4 VGPRs)
typedef __attribute__((ext_vector_type(4))) float f32x4;

#define AS1 __attribute__((address_space(1)))
#define AS3 __attribute__((address_space(3)))

static __device__ __forceinline__ uint32_t f2bf(float f) {
  __hip_bfloat16 h = __float2bfloat16(f);
  return (uint32_t)*reinterpret_cast<unsigned short*>(&h);
}

// ---------------- Kernel 1: router (logits f32, softmax top-1) + x -> bf16 ----
__global__ __launch_bounds__(256) void k_router(
    const float* __restrict__ x, const float* __restrict__ gw,
    __hip_bfloat16* __restrict__ xb, float* __restrict__ logits,
    float* __restrict__ tprob, int* __restrict__ texp) {
  __shared__ __align__(16) float gs[8 * 1024];  // gate weights [e][d]
  const int tid = threadIdx.x;
  {
    const float4* g4 = reinterpret_cast<const float4*>(gw);
    float4* s4 = reinterpret_cast<float4*>(gs);
#pragma unroll
    for (int i = 0; i < 8; ++i) s4[tid + 256 * i] = g4[tid + 256 * i];
  }
  __syncthreads();
  const int wave = tid >> 6, lane = tid & 63;
  const int t = blockIdx.x * 4 + wave;  // one wave per token, 4096 blocks
  const float2* x2 = reinterpret_cast<const float2*>(x + (size_t)t * 1024);
  uint32_t* xbu = reinterpret_cast<uint32_t*>(xb + (size_t)t * 1024);
  const float2* g2 = reinterpret_cast<const float2*>(gs);
  float acc[8];
#pragma unroll
  for (int e = 0; e < 8; ++e) acc[e] = 0.f;
#pragma unroll
  for (int kk = 0; kk < 8; ++kk) {
    int p = lane + 64 * kk;  // float2-pair index, lane-stride-1 (conflict-free LDS)
    float2 xv = x2[p];
    xbu[p] = f2bf(xv.x) | (f2bf(xv.y) << 16);
#pragma unroll
    for (int e = 0; e < 8; ++e) {
      float2 g = g2[e * 512 + p];
      acc[e] = fmaf(xv.x, g.x, acc[e]);
      acc[e] = fmaf(xv.y, g.y, acc[e]);
    }
  }
#pragma unroll
  for (int d = 1; d < 64; d <<= 1) {
#pragma unroll
    for (int e = 0; e < 8; ++e) acc[e] += __shfl_xor(acc[e], d, 64);
  }
  if (lane == 0) {
    float m = acc[0];
    int idx = 0;
#pragma unroll
    for (int e = 1; e < 8; ++e)
      if (acc[e] > m) { m = acc[e]; idx = e; }  // strict '>' == argmax-first tiebreak
    float s = 0.f;
#pragma unroll
    for (int e = 0; e < 8; ++e) s += expf(acc[e] - m);
    tprob[t] = 1.0f / s;   // softmax prob of the max logit
    texp[t] = idx;
#pragma unroll
    for (int e = 0; e < 8; ++e) logits[(size_t)t * 8 + e] = acc[e];
  }
}

// ---------------- Kernel 2: expert_w [e][k][n] f32 -> Wt [e][n][k] bf16 -------
__global__ __launch_bounds__(256) void k_wconv(const float* __restrict__ w,
                                               __hip_bfloat16* __restrict__ wt) {
  // grid = 8 * 32 * 32 tiles of 32x32
  const int bx = blockIdx.x;
  const int e = bx >> 10;
  const int rem = bx & 1023;
  const int k0 = (rem >> 5) << 5;
  const int n0 = (rem & 31) << 5;
  __shared__ float tile[32][33];  // +1 pad: no bank conflicts on transpose
  const int tid = threadIdx.x;
  const int c = tid & 31, r0 = tid >> 5;
  const float* ws = w + (size_t)e * 1024 * 1024;
#pragma unroll
  for (int i = 0; i < 4; ++i) {
    int r = r0 + 8 * i;
    tile[r][c] = ws[(size_t)(k0 + r) * 1024 + n0 + c];
  }
  __syncthreads();
  __hip_bfloat16* wd = wt + (size_t)e * 1024 * 1024;
#pragma unroll
  for (int i = 0; i < 4; ++i) {
    int r = r0 + 8 * i;  // n within tile
    wd[(size_t)(n0 + r) * 1024 + k0 + c] = __float2bfloat16(tile[c][r]);
  }
}

// ---------------- Kernel 3: per-batch capacity scan (cumsum of onehot) --------
__global__ __launch_bounds__(256) void k_scan(
    const int* __restrict__ texp, int* __restrict__ slots, int* __restrict__ neb,
    int* __restrict__ keep, float* __restrict__ idx_out) {
  const int b = blockIdx.x;  // grid = 8
  const int tid = threadIdx.x;
  __shared__ int te_s[2048];
#pragma unroll
  for (int i = 0; i < 8; ++i) te_s[tid + 256 * i] = texp[b * 2048 + tid + 256 * i];
  __syncthreads();

  int myte[8], cnt[8];
#pragma unroll
  for (int e = 0; e < 8; ++e) cnt[e] = 0;
#pragma unroll
  for (int j = 0; j < 8; ++j) {  // thread owns 8 consecutive tokens
    int v = te_s[tid * 8 + j];
    myte[j] = v;
#pragma unroll
    for (int e = 0; e < 8; ++e) cnt[e] += (v == e);
  }
  // pack 8 counters into 4 u32 (16-bit fields; totals <= 2048 < 65536)
  unsigned u0 = (unsigned)cnt[0] | ((unsigned)cnt[1] << 16);
  unsigned u1 = (unsigned)cnt[2] | ((unsigned)cnt[3] << 16);
  unsigned u2 = (unsigned)cnt[4] | ((unsigned)cnt[5] << 16);
  unsigned u3 = (unsigned)cnt[6] | ((unsigned)cnt[7] << 16);
  const int lane = tid & 63, wave = tid >> 6;
#pragma unroll
  for (int d = 1; d < 64; d <<= 1) {  // inclusive scan within wave
    unsigned v0 = __shfl_up(u0, d, 64);
    unsigned v1 = __shfl_up(u1, d, 64);
    unsigned v2 = __shfl_up(u2, d, 64);
    unsigned v3 = __shfl_up(u3, d, 64);
    if (lane >= d) { u0 += v0; u1 += v1; u2 += v2; u3 += v3; }
  }
  __shared__ unsigned wtot[4][4];
  if (lane == 63) { wtot[wave][0] = u0; wtot[wave][1] = u1; wtot[wave][2] = u2; wtot[wave][3] = u3; }
  __syncthreads();
  unsigned a0 = 0, a1 = 0, a2 = 0, a3 = 0, s0 = 0, s1 = 0, s2 = 0, s3 = 0;
#pragma unroll
  for (int w = 0; w < 4; ++w) {
    unsigned q0 = wtot[w][0], q1 = wtot[w][1], q2 = wtot[w][2], q3 = wtot[w][3];
    if (w < wave) { a0 += q0; a1 += q1; a2 += q2; a3 += q3; }
    s0 += q0; s1 += q1; s2 += q2; s3 += q3;
  }
  u0 += a0; u1 += a1; u2 += a2; u3 += a3;  // inclusive over whole block
  int base[8];
  base[0] = (int)(u0 & 0xFFFF) - cnt[0]; base[1] = (int)(u0 >> 16) - cnt[1];
  base[2] = (int)(u1 & 0xFFFF) - cnt[2]; base[3] = (int)(u1 >> 16) - cnt[3];
  base[4] = (int)(u2 & 0xFFFF) - cnt[4]; base[5] = (int)(u2 >> 16) - cnt[5];
  base[6] = (int)(u3 & 0xFFFF) - cnt[6]; base[7] = (int)(u3 >> 16) - cnt[7];
  if (tid == 0) {
    int tt[8] = {(int)(s0 & 0xFFFF), (int)(s0 >> 16), (int)(s1 & 0xFFFF), (int)(s1 >> 16),
                 (int)(s2 & 0xFFFF), (int)(s2 >> 16), (int)(s3 & 0xFFFF), (int)(s3 >> 16)};
#pragma unroll
    for (int e = 0; e < 8; ++e) neb[e * 8 + b] = tt[e] < 512 ? tt[e] : 512;
  }
#pragma unroll
  for (int j = 0; j < 8; ++j) {
    int v = myte[j];
    int rank = 0;
#pragma unroll
    for (int e = 0; e < 8; ++e)
      if (v == e) { base[e] += 1; rank = base[e]; }  // 1-based inclusive rank
    int tok = b * 2048 + tid * 8 + j;
    int kp = rank <= 512;
    keep[tok] = kp;
    idx_out[tok] = kp ? (float)v : 0.0f;  // argmax(all-zero mask)=0 for dropped
    if (kp) slots[v * 4096 + b * 512 + rank - 1] = tok;  // deterministic, no atomics
  }
}

// ---------------- Kernel 3b: compact per-(e,b) segments -> per-e lists --------
__global__ __launch_bounds__(256) void k_compact(
    const int* __restrict__ neb, const int* __restrict__ slots,
    int* __restrict__ comp, int* __restrict__ tot) {
  const int e = blockIdx.x;  // grid = 8
  const int tid = threadIdx.x;
  __shared__ int ofs[8];
  if (tid == 0) {
    int s = 0;
#pragma unroll
    for (int b = 0; b < 8; ++b) { ofs[b] = s; s += neb[e * 8 + b]; }
    tot[e] = s;
  }
  __syncthreads();
#pragma unroll
  for (int b = 0; b < 8; ++b) {
    int c = neb[e * 8 + b];
    int o = ofs[b];
    for (int i = tid; i < c; i += 256)
      comp[e * 4096 + o + i] = slots[e * 4096 + b * 512 + i];
  }
}

// ---------------- Kernel 4: gathered expert GEMM, 128x128xBK64, 2-phase dbuf --
// Per-e compact row lists; tiles = sum_e ceil(tot_e/128)*8 <= 1088.
// LDS: double-buffered A,B [128][64] bf16, linear dest for global_load_lds;
// XOR-swizzle (16B chunk idx ^= row&7) applied on the GLOBAL source + ds_read.
__global__ __launch_bounds__(256, 2) void k_gemm(
    const __hip_bfloat16* __restrict__ xb, const __hip_bfloat16* __restrict__ wt,
    const int* __restrict__ comp, const int* __restrict__ tot,
    const float* __restrict__ tprob, float* __restrict__ out) {
  // uniform tile bookkeeping
  int pf[9];
  pf[0] = 0;
#pragma unroll
  for (int e = 0; e < 8; ++e) pf[e + 1] = pf[e] + ((tot[e] + 127) >> 7) * 8;
  const int T = pf[8];
  const int bid = blockIdx.x;
  if (bid >= T) return;
  // bijective XCD-chunked swizzle (m204): each XCD gets a contiguous tile range
  const int q8 = T >> 3, r8 = T & 7, xcd = bid & 7, pos = bid >> 3;
  const int tile = (xcd < r8 ? xcd * (q8 + 1) : r8 * (q8 + 1) + (xcd - r8) * q8) + pos;
  int e = 0;
#pragma unroll
  for (int k = 0; k < 8; ++k)
    if (tile >= pf[k + 1]) e = k + 1;
  const int local = tile - pf[e];
  const int rt = local >> 3;
  const int ct = local & 7;
  int nvalid = tot[e] - rt * 128;
  if (nvalid > 128) nvalid = 128;

  __shared__ __align__(16) __hip_bfloat16 sm[2][2][128 * 64];  // [buf][A/B][row*64+k]
  __shared__ int rid_s[128];
  __shared__ float tp_s[128];

  const int tid = threadIdx.x;
  const int* seg = comp + e * 4096 + rt * 128;
  if (tid < 128) {
    int rid = seg[(tid < nvalid) ? tid : 0];  // dummy rows -> row 0 (store-masked)
    rid_s[tid] = rid;
    tp_s[tid] = tprob[rid];
  }
  __syncthreads();

  const int wave = tid >> 6, lane = tid & 63;
  const int wm = wave >> 1, wn = wave & 1;  // 2x2 wave grid, 64x64 per wave

  // staging: tile = 1024 chunks of 16B; chunk cid -> LDS byte cid*16 (linear).
  // cid = pass*256+tid: row = cid>>3, slot = cid&7; source k-chunk = slot^(row&7)
  const __hip_bfloat16* wte = wt + (size_t)e * 1024 * 1024;
  const __hip_bfloat16* pa[4];
  const __hip_bfloat16* pb[4];
#pragma unroll
  for (int p = 0; p < 4; ++p) {
    int cid = p * 256 + tid;
    int row = cid >> 3, slot = cid & 7;
    int kl = slot ^ (row & 7);  // involution: swizzled source, linear LDS dest
    pa[p] = xb + (size_t)rid_s[row] * 1024 + kl * 8;
    pb[p] = wte + (size_t)(ct * 128 + row) * 1024 + kl * 8;
  }

#define STAGE(bufi, kti)                                                          \
  do {                                                                            \
    const int koff_ = (kti) * 64;                                                 \
    _Pragma("unroll") for (int p = 0; p < 4; ++p) {                               \
      __builtin_amdgcn_global_load_lds((const AS1 uint32_t*)(pa[p] + koff_),      \
                                       (AS3 uint32_t*)&sm[bufi][0][(p * 256 + tid) * 8], 16, 0, 0); \
      __builtin_amdgcn_global_load_lds((const AS1 uint32_t*)(pb[p] + koff_),      \
                                       (AS3 uint32_t*)&sm[bufi][1][(p * 256 + tid) * 8], 16, 0, 0); \
    }                                                                             \
  } while (0)

  f32x4 acc[4][4];
#pragma unroll
  for (int i = 0; i < 4; ++i)
#pragma unroll
    for (int j = 0; j < 4; ++j) acc[i][j] = 0.f;

  const int frow = lane & 15;
  const int qq = lane >> 4;
  const int sw = frow & 7;
  // element offsets into a [row][64] tile for k-substep ks: slot=(ks*4+qq)^sw
  int aoff[2], boff[2];
#pragma unroll
  for (int ks = 0; ks < 2; ++ks) {
    int slot = (ks * 4 + qq) ^ sw;
    aoff[ks] = (wm * 64 + frow) * 64 + slot * 8;
    boff[ks] = (wn * 64 + frow) * 64 + slot * 8;
  }

  STAGE(0, 0);
  __syncthreads();  // vmcnt(0)+lgkmcnt(0)+barrier: buf0 ready
  int cur = 0;
  for (int kt = 0; kt < 16; ++kt) {
    if (kt < 15) STAGE(cur ^ 1, kt + 1);  // issue next-tile loads BEFORE compute
    const __hip_bfloat16* As = &sm[cur][0][0];
    const __hip_bfloat16* Bs = &sm[cur][1][0];
    __builtin_amdgcn_s_setprio(1);
#pragma unroll
    for (int ks = 0; ks < 2; ++ks) {
      short8 a[4], b[4];
#pragma unroll
      for (int mi = 0; mi < 4; ++mi)
        a[mi] = *reinterpret_cast<const short8*>(&As[aoff[ks] + mi * 16 * 64]);
#pragma unroll
      for (int ni = 0; ni < 4; ++ni)
        b[ni] = *reinterpret_cast<const short8*>(&Bs[boff[ks] + ni * 16 * 64]);
#pragma unroll
      for (int mi = 0; mi < 4; ++mi)
#pragma unroll
        for (int ni = 0; ni < 4; ++ni)
          acc[mi][ni] = __builtin_amdgcn_mfma_f32_16x16x32_bf16(a[mi], b[ni], acc[mi][ni], 0, 0, 0);
    }
    __builtin_amdgcn_s_setprio(0);
    __syncthreads();  // drain stage writes (vmcnt 0) + barrier; next buf ready
    cur ^= 1;
  }
#undef STAGE

  // C/D layout: col = lane&15, row = (lane>>4)*4 + j   [m89-verified]
  const int colb = ct * 128 + wn * 64 + frow;
  const int rowb = wm * 64 + qq * 4;
#pragma unroll
  for (int mi = 0; mi < 4; ++mi) {
#pragma unroll
    for (int j = 0; j < 4; ++j) {
      int r = rowb + mi * 16 + j;
      if (r < nvalid) {
        size_t ro = (size_t)rid_s[r] * 1024;
        float sc = tp_s[r];
#pragma unroll
        for (int ni = 0; ni < 4; ++ni)
          out[ro + colb + ni * 16] = sc * acc[mi][ni][j];
      }
    }
  }
}

// ---------------- Kernel 5: identity pass-through for dropped tokens ----------
__global__ __launch_bounds__(256) void k_identity(
    const float* __restrict__ x, const float* __restrict__ tprob,
    const int* __restrict__ keep, float* __restrict__ out) {
  const int t0 = blockIdx.x * 8;  // grid = 2048
  const int tid = threadIdx.x;
#pragma unroll
  for (int j = 0; j < 8; ++j) {
    int t = t0 + j;
    if (!keep[t]) {
      float s = tprob[t];
      const float4* xi = reinterpret_cast<const float4*>(x + (size_t)t * 1024);
      float4* o = reinterpret_cast<float4*>(out + (size_t)t * 1024);
      float4 v = xi[tid];
      o[tid] = make_float4(s * v.x, s * v.y, s * v.z, s * v.w);
    }
  }
}

extern "C" void kernel_launch(void* const* d_in, const int* in_sizes, int n_in,
                              void* d_out, int out_size, void* d_ws, size_t ws_size,
                              hipStream_t stream) {
  const float* x = (const float*)d_in[0];    // [8,2048,1024]
  const float* gw = (const float*)d_in[1];   // [8,1024]
  const float* w = (const float*)d_in[2];    // [8,1024,1024]
  float* out = (float*)d_out;
  float* logits = out + (size_t)16384 * 1024;
  float* idx_out = logits + (size_t)16384 * 8;

  // workspace layout (~50.8 MB total)
  char* ws = (char*)d_ws;
  __hip_bfloat16* xb = (__hip_bfloat16*)(ws);              // 33554432 B
  __hip_bfloat16* wt = (__hip_bfloat16*)(ws + 33554432);   // 16777216 B
  float* tprob = (float*)(ws + 50331648);                  // 65536 B
  int* texp   = (int*)(ws + 50397184);                     // 65536 B
  int* keep   = (int*)(ws + 50462720);                     // 65536 B
  int* slots  = (int*)(ws + 50528256);                     // 131072 B
  int* neb    = (int*)(ws + 50659328);                     // 256 B
  int* comp   = (int*)(ws + 50659584);                     // 131072 B
  int* tot    = (int*)(ws + 50790656);                     // 32 B

  hipLaunchKernelGGL(k_router,   dim3(4096), dim3(256), 0, stream, x, gw, xb, logits, tprob, texp);
  hipLaunchKernelGGL(k_wconv,    dim3(8192), dim3(256), 0, stream, w, wt);
  hipLaunchKernelGGL(k_scan,     dim3(8),    dim3(256), 0, stream, texp, slots, neb, keep, idx_out);
  hipLaunchKernelGGL(k_compact,  dim3(8),    dim3(256), 0, stream, neb, slots, comp, tot);
  hipLaunchKernelGGL(k_gemm,     dim3(1088), dim3(256), 0, stream, xb, wt, comp, tot, tprob, out);
  hipLaunchKernelGGL(k_identity, dim3(2048), dim3(256), 0, stream, x, tprob, keep, out);
}

// Round 3
// 111.118 us; speedup vs baseline: 1.2993x; 1.0207x over previous
//
#include <hip/hip_runtime.h>
#include <hip/hip_bf16.h>
#include <stdint.h>

// Problem: B=8, S=2048, D=1024, E=8, CAP=512, TOK=16384.
// Outputs (concat f32): hidden[16384*1024], logits[16384*8], expert_index[16384]

typedef __attribute__((ext_vector_type(8))) short short8;   // 8 x bf16 (4 VGPRs)
typedef __attribute__((ext_vector_type(4))) float f32x4;

#define AS1 __attribute__((address_space(1)))
#define AS3 __attribute__((address_space(3)))

static __device__ __forceinline__ uint32_t f2bf(float f) {
  __hip_bfloat16 h = __float2bfloat16(f);
  return (uint32_t)*reinterpret_cast<unsigned short*>(&h);
}

// ---------------- Kernel 1: router (logits f32, softmax top-1) + x -> bf16 ----
__global__ __launch_bounds__(256) void k_router(
    const float* __restrict__ x, const float* __restrict__ gw,
    __hip_bfloat16* __restrict__ xb, float* __restrict__ logits,
    float* __restrict__ tprob, int* __restrict__ texp) {
  __shared__ __align__(16) float gs[8 * 1024];  // gate weights [e][d]
  const int tid = threadIdx.x;
  {
    const float4* g4 = reinterpret_cast<const float4*>(gw);
    float4* s4 = reinterpret_cast<float4*>(gs);
#pragma unroll
    for (int i = 0; i < 8; ++i) s4[tid + 256 * i] = g4[tid + 256 * i];
  }
  __syncthreads();
  const int wave = tid >> 6, lane = tid & 63;
  const int t = blockIdx.x * 4 + wave;  // one wave per token, 4096 blocks
  const float2* x2 = reinterpret_cast<const float2*>(x + (size_t)t * 1024);
  uint32_t* xbu = reinterpret_cast<uint32_t*>(xb + (size_t)t * 1024);
  const float2* g2 = reinterpret_cast<const float2*>(gs);
  float acc[8];
#pragma unroll
  for (int e = 0; e < 8; ++e) acc[e] = 0.f;
#pragma unroll
  for (int kk = 0; kk < 8; ++kk) {
    int p = lane + 64 * kk;  // float2-pair index, lane-stride-1 (conflict-free LDS)
    float2 xv = x2[p];
    xbu[p] = f2bf(xv.x) | (f2bf(xv.y) << 16);
#pragma unroll
    for (int e = 0; e < 8; ++e) {
      float2 g = g2[e * 512 + p];
      acc[e] = fmaf(xv.x, g.x, acc[e]);
      acc[e] = fmaf(xv.y, g.y, acc[e]);
    }
  }
#pragma unroll
  for (int d = 1; d < 64; d <<= 1) {
#pragma unroll
    for (int e = 0; e < 8; ++e) acc[e] += __shfl_xor(acc[e], d, 64);
  }
  if (lane == 0) {
    float m = acc[0];
    int idx = 0;
#pragma unroll
    for (int e = 1; e < 8; ++e)
      if (acc[e] > m) { m = acc[e]; idx = e; }  // strict '>' == argmax-first tiebreak
    float s = 0.f;
#pragma unroll
    for (int e = 0; e < 8; ++e) s += expf(acc[e] - m);
    tprob[t] = 1.0f / s;   // softmax prob of the max logit
    texp[t] = idx;
#pragma unroll
    for (int e = 0; e < 8; ++e) logits[(size_t)t * 8 + e] = acc[e];
  }
}

// ---------------- Kernel 2: expert_w [e][k][n] f32 -> Wt [e][n][k] bf16 -------
__global__ __launch_bounds__(256) void k_wconv(const float* __restrict__ w,
                                               __hip_bfloat16* __restrict__ wt) {
  // grid = 8 * 32 * 32 tiles of 32x32
  const int bx = blockIdx.x;
  const int e = bx >> 10;
  const int rem = bx & 1023;
  const int k0 = (rem >> 5) << 5;
  const int n0 = (rem & 31) << 5;
  __shared__ float tile[32][33];  // +1 pad: no bank conflicts on transpose
  const int tid = threadIdx.x;
  const int c = tid & 31, r0 = tid >> 5;
  const float* ws = w + (size_t)e * 1024 * 1024;
#pragma unroll
  for (int i = 0; i < 4; ++i) {
    int r = r0 + 8 * i;
    tile[r][c] = ws[(size_t)(k0 + r) * 1024 + n0 + c];
  }
  __syncthreads();
  __hip_bfloat16* wd = wt + (size_t)e * 1024 * 1024;
#pragma unroll
  for (int i = 0; i < 4; ++i) {
    int r = r0 + 8 * i;  // n within tile
    wd[(size_t)(n0 + r) * 1024 + k0 + c] = __float2bfloat16(tile[c][r]);
  }
}

// ---------------- Kernel 3: per-batch capacity scan (cumsum of onehot) --------
__global__ __launch_bounds__(256) void k_scan(
    const int* __restrict__ texp, int* __restrict__ slots, int* __restrict__ neb,
    int* __restrict__ keep, float* __restrict__ idx_out) {
  const int b = blockIdx.x;  // grid = 8
  const int tid = threadIdx.x;
  __shared__ int te_s[2048];
#pragma unroll
  for (int i = 0; i < 8; ++i) te_s[tid + 256 * i] = texp[b * 2048 + tid + 256 * i];
  __syncthreads();

  int myte[8], cnt[8];
#pragma unroll
  for (int e = 0; e < 8; ++e) cnt[e] = 0;
#pragma unroll
  for (int j = 0; j < 8; ++j) {  // thread owns 8 consecutive tokens
    int v = te_s[tid * 8 + j];
    myte[j] = v;
#pragma unroll
    for (int e = 0; e < 8; ++e) cnt[e] += (v == e);
  }
  // pack 8 counters into 4 u32 (16-bit fields; totals <= 2048 < 65536)
  unsigned u0 = (unsigned)cnt[0] | ((unsigned)cnt[1] << 16);
  unsigned u1 = (unsigned)cnt[2] | ((unsigned)cnt[3] << 16);
  unsigned u2 = (unsigned)cnt[4] | ((unsigned)cnt[5] << 16);
  unsigned u3 = (unsigned)cnt[6] | ((unsigned)cnt[7] << 16);
  const int lane = tid & 63, wave = tid >> 6;
#pragma unroll
  for (int d = 1; d < 64; d <<= 1) {  // inclusive scan within wave
    unsigned v0 = __shfl_up(u0, d, 64);
    unsigned v1 = __shfl_up(u1, d, 64);
    unsigned v2 = __shfl_up(u2, d, 64);
    unsigned v3 = __shfl_up(u3, d, 64);
    if (lane >= d) { u0 += v0; u1 += v1; u2 += v2; u3 += v3; }
  }
  __shared__ unsigned wtot[4][4];
  if (lane == 63) { wtot[wave][0] = u0; wtot[wave][1] = u1; wtot[wave][2] = u2; wtot[wave][3] = u3; }
  __syncthreads();
  unsigned a0 = 0, a1 = 0, a2 = 0, a3 = 0, s0 = 0, s1 = 0, s2 = 0, s3 = 0;
#pragma unroll
  for (int w = 0; w < 4; ++w) {
    unsigned q0 = wtot[w][0], q1 = wtot[w][1], q2 = wtot[w][2], q3 = wtot[w][3];
    if (w < wave) { a0 += q0; a1 += q1; a2 += q2; a3 += q3; }
    s0 += q0; s1 += q1; s2 += q2; s3 += q3;
  }
  u0 += a0; u1 += a1; u2 += a2; u3 += a3;  // inclusive over whole block
  int base[8];
  base[0] = (int)(u0 & 0xFFFF) - cnt[0]; base[1] = (int)(u0 >> 16) - cnt[1];
  base[2] = (int)(u1 & 0xFFFF) - cnt[2]; base[3] = (int)(u1 >> 16) - cnt[3];
  base[4] = (int)(u2 & 0xFFFF) - cnt[4]; base[5] = (int)(u2 >> 16) - cnt[5];
  base[6] = (int)(u3 & 0xFFFF) - cnt[6]; base[7] = (int)(u3 >> 16) - cnt[7];
  if (tid == 0) {
    int tt[8] = {(int)(s0 & 0xFFFF), (int)(s0 >> 16), (int)(s1 & 0xFFFF), (int)(s1 >> 16),
                 (int)(s2 & 0xFFFF), (int)(s2 >> 16), (int)(s3 & 0xFFFF), (int)(s3 >> 16)};
#pragma unroll
    for (int e = 0; e < 8; ++e) neb[e * 8 + b] = tt[e] < 512 ? tt[e] : 512;
  }
#pragma unroll
  for (int j = 0; j < 8; ++j) {
    int v = myte[j];
    int rank = 0;
#pragma unroll
    for (int e = 0; e < 8; ++e)
      if (v == e) { base[e] += 1; rank = base[e]; }  // 1-based inclusive rank
    int tok = b * 2048 + tid * 8 + j;
    int kp = rank <= 512;
    keep[tok] = kp;
    idx_out[tok] = kp ? (float)v : 0.0f;  // argmax(all-zero mask)=0 for dropped
    if (kp) slots[v * 4096 + b * 512 + rank - 1] = tok;  // deterministic, no atomics
  }
}

// ---------------- Kernel 3b: compact per-(e,b) segments -> per-e lists --------
__global__ __launch_bounds__(256) void k_compact(
    const int* __restrict__ neb, const int* __restrict__ slots,
    int* __restrict__ comp, int* __restrict__ tot) {
  const int e = blockIdx.x;  // grid = 8
  const int tid = threadIdx.x;
  __shared__ int ofs[8];
  if (tid == 0) {
    int s = 0;
#pragma unroll
    for (int b = 0; b < 8; ++b) { ofs[b] = s; s += neb[e * 8 + b]; }
    tot[e] = s;
  }
  __syncthreads();
#pragma unroll
  for (int b = 0; b < 8; ++b) {
    int c = neb[e * 8 + b];
    int o = ofs[b];
    for (int i = tid; i < c; i += 256)
      comp[e * 4096 + o + i] = slots[e * 4096 + b * 512 + i];
  }
}

// ---------------- Kernel 4: gathered expert GEMM, 128x128xBK32 ----------------
// 3 LDS buffers, prefetch depth 2, counted s_waitcnt vmcnt(4) (T4) — never
// drain-to-0 in the main loop. Stage of tile t+2 targets buf[(t+2)%3] which
// differs from the current read buffer, so the only clobber guard is
// lgkmcnt(0)+sched_barrier before the single per-iter s_barrier (rule 18).
// Swizzle: 16B chunk slot' = slot ^ ((row>>1)&3) — involution applied on the
// pre-swizzled GLOBAL source and on the ds_read side (rule 21); spreads each
// 16-lane quarter across all 8 LDS 16B-slot positions (conflict-free).
__global__ __launch_bounds__(256, 3) void k_gemm(
    const __hip_bfloat16* __restrict__ xb, const __hip_bfloat16* __restrict__ wt,
    const int* __restrict__ comp, const int* __restrict__ tot,
    const float* __restrict__ tprob, float* __restrict__ out) {
  int pf[9];
  pf[0] = 0;
#pragma unroll
  for (int e = 0; e < 8; ++e) pf[e + 1] = pf[e] + ((tot[e] + 127) >> 7) * 8;
  const int T = pf[8];
  const int bid = blockIdx.x;
  if (bid >= T) return;
  // bijective XCD-chunked swizzle (m204)
  const int q8 = T >> 3, r8 = T & 7, xcd = bid & 7, pos = bid >> 3;
  const int tile = (xcd < r8 ? xcd * (q8 + 1) : r8 * (q8 + 1) + (xcd - r8) * q8) + pos;
  int e = 0;
#pragma unroll
  for (int k = 0; k < 8; ++k)
    if (tile >= pf[k + 1]) e = k + 1;
  const int local = tile - pf[e];
  const int rt = local >> 3;
  const int ct = local & 7;
  int nvalid = tot[e] - rt * 128;
  if (nvalid > 128) nvalid = 128;

  __shared__ __align__(16) __hip_bfloat16 sm[3][2][128 * 32];  // 48 KiB
  __shared__ int rid_s[128];
  __shared__ float tp_s[128];

  const int tid = threadIdx.x;
  const int* seg = comp + e * 4096 + rt * 128;
  if (tid < 128) {
    int rid = seg[(tid < nvalid) ? tid : 0];  // dummy rows -> row 0 (store-masked)
    rid_s[tid] = rid;
    tp_s[tid] = tprob[rid];
  }
  __syncthreads();

  const int wave = tid >> 6, lane = tid & 63;
  const int wm = wave >> 1, wn = wave & 1;  // 2x2 wave grid, 64x64 per wave

  // staging: tile = 512 chunks of 16B (128 rows x 4 chunks); linear LDS dest,
  // swizzled global source: kl = slot ^ ((row>>1)&3)
  const __hip_bfloat16* wte = wt + (size_t)e * 1024 * 1024;
  const __hip_bfloat16* pa[2];
  const __hip_bfloat16* pb[2];
#pragma unroll
  for (int p = 0; p < 2; ++p) {
    int cid = p * 256 + tid;
    int row = cid >> 2, slot = cid & 3;
    int kl = slot ^ ((row >> 1) & 3);
    pa[p] = xb + (size_t)rid_s[row] * 1024 + kl * 8;
    pb[p] = wte + (size_t)(ct * 128 + row) * 1024 + kl * 8;
  }

#define STAGE(kti, bufi)                                                           \
  do {                                                                             \
    _Pragma("unroll") for (int p = 0; p < 2; ++p) {                                \
      __builtin_amdgcn_global_load_lds((const AS1 uint32_t*)(pa[p] + (kti) * 32),  \
                                       (AS3 uint32_t*)&sm[bufi][0][(p * 256 + tid) * 8], 16, 0, 0); \
      __builtin_amdgcn_global_load_lds((const AS1 uint32_t*)(pb[p] + (kti) * 32),  \
                                       (AS3 uint32_t*)&sm[bufi][1][(p * 256 + tid) * 8], 16, 0, 0); \
    }                                                                              \
  } while (0)

  f32x4 acc[4][4];
#pragma unroll
  for (int i = 0; i < 4; ++i)
#pragma unroll
    for (int j = 0; j < 4; ++j) acc[i][j] = 0.f;

  const int frow = lane & 15;
  const int qq = lane >> 4;
  const int sl = qq ^ ((frow >> 1) & 3);  // read-side swizzle (same involution)
  const int aoff = (wm * 64 + frow) * 32 + sl * 8;
  const int boff = (wn * 64 + frow) * 32 + sl * 8;

  STAGE(0, 0);
  STAGE(1, 1);

#define COMPUTE(bufi)                                                              \
  do {                                                                             \
    const __hip_bfloat16* As = &sm[bufi][0][0];                                    \
    const __hip_bfloat16* Bs = &sm[bufi][1][0];                                    \
    short8 a[4], b[4];                                                             \
    _Pragma("unroll") for (int mi = 0; mi < 4; ++mi)                               \
        a[mi] = *reinterpret_cast<const short8*>(&As[aoff + mi * 512]);            \
    _Pragma("unroll") for (int ni = 0; ni < 4; ++ni)                               \
        b[ni] = *reinterpret_cast<const short8*>(&Bs[boff + ni * 512]);            \
    asm volatile("s_waitcnt lgkmcnt(0)" ::: "memory");                             \
    __builtin_amdgcn_sched_barrier(0);                                             \
    __builtin_amdgcn_s_setprio(1);                                                 \
    _Pragma("unroll") for (int mi = 0; mi < 4; ++mi)                               \
        _Pragma("unroll") for (int ni = 0; ni < 4; ++ni)                           \
            acc[mi][ni] = __builtin_amdgcn_mfma_f32_16x16x32_bf16(a[mi], b[ni], acc[mi][ni], 0, 0, 0); \
    __builtin_amdgcn_s_setprio(0);                                                 \
  } while (0)

  for (int t = 0; t < 31; ++t) {
    // tile t resident after draining to <=4 outstanding (t+1's 4 loads remain)
    asm volatile("s_waitcnt vmcnt(4)" ::: "memory");
    __builtin_amdgcn_s_barrier();
    if (t + 2 < 32) STAGE(t + 2, (t + 2) % 3);
    COMPUTE(t % 3);
  }
  // t = 31: nothing left in flight except tile 31's own loads
  asm volatile("s_waitcnt vmcnt(0)" ::: "memory");
  __builtin_amdgcn_s_barrier();
  COMPUTE(31 % 3);
#undef COMPUTE
#undef STAGE

  // C/D layout: col = lane&15, row = (lane>>4)*4 + j   [m89-verified]
  const int colb = ct * 128 + wn * 64 + frow;
  const int rowb = wm * 64 + qq * 4;
#pragma unroll
  for (int mi = 0; mi < 4; ++mi) {
#pragma unroll
    for (int j = 0; j < 4; ++j) {
      int r = rowb + mi * 16 + j;
      if (r < nvalid) {
        size_t ro = (size_t)rid_s[r] * 1024;
        float sc = tp_s[r];
#pragma unroll
        for (int ni = 0; ni < 4; ++ni)
          out[ro + colb + ni * 16] = sc * acc[mi][ni][j];
      }
    }
  }
}

// ---------------- Kernel 5: identity pass-through for dropped tokens ----------
__global__ __launch_bounds__(256) void k_identity(
    const float* __restrict__ x, const float* __restrict__ tprob,
    const int* __restrict__ keep, float* __restrict__ out) {
  const int t0 = blockIdx.x * 8;  // grid = 2048
  const int tid = threadIdx.x;
#pragma unroll
  for (int j = 0; j < 8; ++j) {
    int t = t0 + j;
    if (!keep[t]) {
      float s = tprob[t];
      const float4* xi = reinterpret_cast<const float4*>(x + (size_t)t * 1024);
      float4* o = reinterpret_cast<float4*>(out + (size_t)t * 1024);
      float4 v = xi[tid];
      o[tid] = make_float4(s * v.x, s * v.y, s * v.z, s * v.w);
    }
  }
}

extern "C" void kernel_launch(void* const* d_in, const int* in_sizes, int n_in,
                              void* d_out, int out_size, void* d_ws, size_t ws_size,
                              hipStream_t stream) {
  const float* x = (const float*)d_in[0];    // [8,2048,1024]
  const float* gw = (const float*)d_in[1];   // [8,1024]
  const float* w = (const float*)d_in[2];    // [8,1024,1024]
  float* out = (float*)d_out;
  float* logits = out + (size_t)16384 * 1024;
  float* idx_out = logits + (size_t)16384 * 8;

  // workspace layout (~50.8 MB total)
  char* ws = (char*)d_ws;
  __hip_bfloat16* xb = (__hip_bfloat16*)(ws);              // 33554432 B
  __hip_bfloat16* wt = (__hip_bfloat16*)(ws + 33554432);   // 16777216 B
  float* tprob = (float*)(ws + 50331648);                  // 65536 B
  int* texp   = (int*)(ws + 50397184);                     // 65536 B
  int* keep   = (int*)(ws + 50462720);                     // 65536 B
  int* slots  = (int*)(ws + 50528256);                     // 131072 B
  int* neb    = (int*)(ws + 50659328);                     // 256 B
  int* comp   = (int*)(ws + 50659584);                     // 131072 B
  int* tot    = (int*)(ws + 50790656);                     // 32 B

  hipLaunchKernelGGL(k_router,   dim3(4096), dim3(256), 0, stream, x, gw, xb, logits, tprob, texp);
  hipLaunchKernelGGL(k_wconv,    dim3(8192), dim3(256), 0, stream, w, wt);
  hipLaunchKernelGGL(k_scan,     dim3(8),    dim3(256), 0, stream, texp, slots, neb, keep, idx_out);
  hipLaunchKernelGGL(k_compact,  dim3(8),    dim3(256), 0, stream, neb, slots, comp, tot);
  hipLaunchKernelGGL(k_gemm,     dim3(1088), dim3(256), 0, stream, xb, wt, comp, tot, tprob, out);
  hipLaunchKernelGGL(k_identity, dim3(2048), dim3(256), 0, stream, x, tprob, keep, out);
}